// Round 4
// baseline (1402.792 us; speedup 1.0000x reference)
//
#include <hip/hip_runtime.h>

// VQ-VAE vector quantizer step on MI355X (gfx950).
// Round 6: coarse argmin without LDS/barriers + parallel scan.
//   - argmin_coarse_k: B-fragments read directly from the pre-swizzled
//     global eswz (512 KB, L1/L2-resident; byte-identical values to the
//     round-5 LDS path, so numerics unchanged). No __syncthreads in the
//     K-loop -> no vmcnt(0) barrier drains; 32 independent tile iters.
//   - scan_k: wave-parallel exclusive prefix sum (was serial 1-thread).
// All other kernels byte-identical to the round-5 passing version.

#define NT 131072   // tokens
#define NE 1024     // codebook entries
#define ED 256      // embedding dim

typedef _Float16 f16;
typedef f16  f16x8 __attribute__((ext_vector_type(8)));
typedef float f32x4 __attribute__((ext_vector_type(4)));

// Output layout (flat f32, reference return order)
static const size_t OFF_QL   = 0;            // quant_loss (1)
static const size_t OFF_CL   = 1;            // commit_loss (1)
static const size_t OFF_ZQ   = 2;            // z_q_st (131072*256)
static const size_t OFF_PPL  = 33554434ULL;  // perplexity (1)
static const size_t OFF_OH   = 33554435ULL;  // min_encodings (131072*1024)
static const size_t OFF_IDX  = 167772163ULL; // idx (131072)
static const size_t OFF_NEMB = 167903235ULL; // new_emb_weight (1024*256)
static const size_t OFF_NN   = 168165379ULL; // new_n_mat (1024)
static const size_t OFF_NM   = 168166403ULL; // new_m_mat (1024*256)

// ---------------------------------------------------------------- row norms
__global__ __launch_bounds__(256) void rownorm_k(const float* __restrict__ x,
                                                 float* __restrict__ o, int nrows) {
  int wid  = blockIdx.x * 4 + (threadIdx.x >> 6);  // one wave per row
  int lane = threadIdx.x & 63;
  if (wid >= nrows) return;
  float4 v = ((const float4*)(x + (size_t)wid * ED))[lane];
  float s = v.x * v.x + v.y * v.y + v.z * v.z + v.w * v.w;
  #pragma unroll
  for (int off = 32; off; off >>= 1) s += __shfl_down(s, off, 64);
  if (lane == 0) o[wid] = s;
}

// ------------------------------------- codebook prep: f16 (e*1024) swizzled
// Tile t (32 codes) = contiguous 16 KB block; 16B unit
// g = (c_local<<5) | (kq ^ (c_local&7)) holds e[c][8*kq .. 8*kq+8).
__global__ __launch_bounds__(256) void eprep_k(const float* __restrict__ emb,
                                               char* __restrict__ eswz) {
  const int t  = threadIdx.x;
  const int c  = blockIdx.x * 8 + (t >> 5);   // code
  const int kq = t & 31;                      // 8-elem unit within row
  const float* er = emb + (size_t)c * ED + kq * 8;
  float4 v0 = ((const float4*)er)[0];
  float4 v1 = ((const float4*)er)[1];
  float vv[8] = {v0.x, v0.y, v0.z, v0.w, v1.x, v1.y, v1.z, v1.w};
  f16x8 h;
  #pragma unroll
  for (int i = 0; i < 8; ++i) h[i] = (f16)(vv[i] * 1024.0f);  // exact pow2 scale
  const int tile = c >> 5, cl = c & 31;
  const int g = (cl << 5) | (kq ^ (cl & 7));
  *(f16x8*)(eswz + (size_t)tile * 16384 + (size_t)g * 16) = h;
}

// --------------------------------------------- coarse MFMA distance argmin
// dd_j = ||e_j||^2 - 2 z.e_j  (token-invariant ||z||^2 dropped).
// B-fragments straight from global eswz; per-lane byte offset inside a tile:
//   off(kt,nf) = lr*512 + nf*8192 + ((kt*4+kg)^(lr&7))*16
// == the u*16 the round-5 LDS reader used (cl = nf*16+lr; cl&7 == lr&7;
// cl*512 == lr*512 + nf*8192) -> identical bytes, identical numerics.
__global__ __launch_bounds__(256) void argmin_coarse_k(
    const float* __restrict__ z, const char* __restrict__ eswz,
    const float* __restrict__ enorm, int* __restrict__ idxw,
    int* __restrict__ nflag, int* __restrict__ flaglist) {
  const int tid  = threadIdx.x;
  const int w    = tid >> 6, lane = tid & 63;
  const int lr   = lane & 15, kg = lane >> 4;
  const int r0   = blockIdx.x * 128 + w * 32;

  // A fragments: row = lane&15, k = kt*32 + kg*8 + i  (validated rounds 2/5)
  f16x8 ah[2][8];
  #pragma unroll
  for (int mf = 0; mf < 2; ++mf) {
    const float* zr = z + (size_t)(r0 + mf * 16 + lr) * ED + kg * 8;
    #pragma unroll
    for (int kt = 0; kt < 8; ++kt) {
      float4 a = ((const float4*)(zr + kt * 32))[0];
      float4 b = ((const float4*)(zr + kt * 32))[1];
      float vv[8] = {a.x, a.y, a.z, a.w, b.x, b.y, b.z, b.w};
      #pragma unroll
      for (int i = 0; i < 8; ++i) ah[mf][kt][i] = (f16)vv[i];
    }
  }

  // per-lane byte offsets for B loads within a tile
  const int xr = lr & 7;
  int boff[8];
  #pragma unroll
  for (int kt = 0; kt < 8; ++kt)
    boff[kt] = lr * 512 + (((kt * 4 + kg) ^ xr) << 4);

  float m1[2][4], m2[2][4]; int i1[2][4];
  #pragma unroll
  for (int mf = 0; mf < 2; ++mf)
    #pragma unroll
    for (int r = 0; r < 4; ++r) {
      m1[mf][r] = 3.4028235e38f; m2[mf][r] = 3.4028235e38f; i1[mf][r] = 0;
    }

  for (int ct = 0; ct < 32; ++ct) {
    const char* tb = eswz + (size_t)ct * 16384;

    f32x4 acc[2][2];
    #pragma unroll
    for (int mf = 0; mf < 2; ++mf)
      #pragma unroll
      for (int nf = 0; nf < 2; ++nf) acc[mf][nf] = (f32x4){0.f, 0.f, 0.f, 0.f};

    #pragma unroll
    for (int kt = 0; kt < 8; ++kt) {
      f16x8 b0, b1;
      __builtin_memcpy(&b0, tb + boff[kt], 16);
      __builtin_memcpy(&b1, tb + boff[kt] + 8192, 16);
      acc[0][0] = __builtin_amdgcn_mfma_f32_16x16x32_f16(ah[0][kt], b0, acc[0][0], 0, 0, 0);
      acc[1][0] = __builtin_amdgcn_mfma_f32_16x16x32_f16(ah[1][kt], b0, acc[1][0], 0, 0, 0);
      acc[0][1] = __builtin_amdgcn_mfma_f32_16x16x32_f16(ah[0][kt], b1, acc[0][1], 0, 0, 0);
      acc[1][1] = __builtin_amdgcn_mfma_f32_16x16x32_f16(ah[1][kt], b1, acc[1][1], 0, 0, 0);
    }

    // C/D: col = lane&15, row = kg*4 + r
    #pragma unroll
    for (int nf = 0; nf < 2; ++nf) {
      const int c = ct * 32 + nf * 16 + lr;
      const float en = enorm[c];
      #pragma unroll
      for (int mf = 0; mf < 2; ++mf)
        #pragma unroll
        for (int r = 0; r < 4; ++r) {
          float dd = en - 0.001953125f * acc[mf][nf][r];   // en - 2*dot
          if (dd < m1[mf][r]) {
            m2[mf][r] = m1[mf][r]; m1[mf][r] = dd; i1[mf][r] = c;
          } else if (dd < m2[mf][r]) {
            m2[mf][r] = dd;
          }
        }
    }
  }

  // reduce (min1,min2) across the 16 column-lanes (lane bits 0..3)
  #pragma unroll
  for (int mf = 0; mf < 2; ++mf)
    #pragma unroll
    for (int r = 0; r < 4; ++r) {
      float a1 = m1[mf][r]; int ai = i1[mf][r]; float a2 = m2[mf][r];
      #pragma unroll
      for (int off = 1; off < 16; off <<= 1) {
        float o1 = __shfl_xor(a1, off, 64);
        int   oi = __shfl_xor(ai, off, 64);
        float o2 = __shfl_xor(a2, off, 64);
        if (o1 < a1) { a2 = fminf(a1, o2); a1 = o1; ai = oi; }
        else         { a2 = fminf(a2, o1); }
      }
      if (lr == 0) {
        const int row = r0 + mf * 16 + kg * 4 + r;
        idxw[row] = ai;                          // provisional if flagged
        if (a2 - a1 < 4.0e-4f) {
          int p = atomicAdd(nflag, 1);
          flaglist[p] = row;
        }
      }
    }
}

// ------------------------- exact fp32 refine (round-1 arithmetic) for flags
__global__ __launch_bounds__(256) void argmin_refine_k(
    const float* __restrict__ z, const float* __restrict__ emb,
    const float* __restrict__ znorm, const float* __restrict__ enorm,
    const int* __restrict__ nflag, const int* __restrict__ flaglist,
    int* __restrict__ idxw) {
  const int nf = *nflag;
  const int b0 = blockIdx.x * 16;
  if (b0 >= nf) return;

  __shared__ float zl[16][256];    // 16 KB staged z rows
  __shared__ int   toks[16];
  __shared__ float rv[4][16];
  __shared__ int   ri[4][16];

  const int t = threadIdx.x;
  if (t < 16) {
    int li = b0 + t;
    toks[t] = flaglist[li < nf ? li : b0];   // tail clamps to a valid token
  }
  __syncthreads();

  #pragma unroll
  for (int i = 0; i < 4; ++i) {
    int li = t + i * 256;                    // 0..1023 float4 units
    int row = li >> 6, c4 = li & 63;
    float4 v = ((const float4*)(z + (size_t)toks[row] * ED))[c4];
    *(float4*)&zl[row][c4 * 4] = v;
  }
  __syncthreads();

  float acc[4][16];
  #pragma unroll
  for (int cc = 0; cc < 4; ++cc)
    #pragma unroll
    for (int tk = 0; tk < 16; ++tk) acc[cc][tk] = 0.f;

  for (int c4 = 0; c4 < 64; ++c4) {
    float4 e[4];
    #pragma unroll
    for (int cc = 0; cc < 4; ++cc)
      e[cc] = ((const float4*)(emb + (size_t)(t * 4 + cc) * ED))[c4];
    #pragma unroll
    for (int tk = 0; tk < 16; ++tk) {
      float4 zv = *(const float4*)&zl[tk][c4 * 4];
      #pragma unroll
      for (int cc = 0; cc < 4; ++cc) {
        acc[cc][tk] += zv.x * e[cc].x;
        acc[cc][tk] += zv.y * e[cc].y;
        acc[cc][tk] += zv.z * e[cc].z;
        acc[cc][tk] += zv.w * e[cc].w;
      }
    }
  }

  float en[4];
  #pragma unroll
  for (int cc = 0; cc < 4; ++cc) en[cc] = enorm[t * 4 + cc];

  const int wv = t >> 6, lane = t & 63;
  for (int tk = 0; tk < 16; ++tk) {
    const float zn = znorm[toks[tk]];
    float bv = 3.4028235e38f; int bi = 0;
    #pragma unroll
    for (int cc = 0; cc < 4; ++cc) {
      float s = zn + en[cc];                  // exact round-1 expression
      float d = s - 2.0f * acc[cc][tk];
      int   c = t * 4 + cc;
      if (d < bv) { bv = d; bi = c; }
    }
    #pragma unroll
    for (int off = 32; off; off >>= 1) {
      float ov = __shfl_down(bv, off, 64);
      int   oi = __shfl_down(bi, off, 64);
      if (ov < bv || (ov == bv && oi < bi)) { bv = ov; bi = oi; }
    }
    if (lane == 0) { rv[wv][tk] = bv; ri[wv][tk] = bi; }
  }
  __syncthreads();
  if (t < 16) {
    float bv = rv[0][t]; int bi = ri[0][t];
    #pragma unroll
    for (int wq = 1; wq < 4; ++wq) {
      float ov = rv[wq][t]; int oi = ri[wq][t];
      if (ov < bv || (ov == bv && oi < bi)) { bv = ov; bi = oi; }
    }
    idxw[toks[t]] = bi;
  }
}

// ------------------------- streaming per-token outputs: z_q, one-hot, loss
__global__ __launch_bounds__(256) void zq_oh_k(
    const float* __restrict__ z, const float* __restrict__ emb,
    const int* __restrict__ idxw, float* __restrict__ out,
    double* __restrict__ lossacc) {
  const int t = threadIdx.x;
  const int tl = t >> 6, lane = t & 63;
  const int tok = blockIdx.x * 4 + tl;
  const int id = idxw[tok];

  float4 z4 = ((const float4*)(z   + (size_t)tok * ED))[lane];
  float4 e4 = ((const float4*)(emb + (size_t)id  * ED))[lane];
  float4 q;
  q.x = z4.x + (e4.x - z4.x);   // straight-through, exact ref formula
  q.y = z4.y + (e4.y - z4.y);
  q.z = z4.z + (e4.z - z4.z);
  q.w = z4.w + (e4.w - z4.w);
  __builtin_memcpy(out + OFF_ZQ + (size_t)tok * ED + (size_t)lane * 4, &q, 16);

  float dx = e4.x - z4.x, dy = e4.y - z4.y, dz = e4.z - z4.z, dw = e4.w - z4.w;
  double lsum = (double)(dx * dx) + (double)(dy * dy)
              + (double)(dz * dz) + (double)(dw * dw);

  float* ohb = out + OFF_OH + (size_t)tok * NE;
  #pragma unroll
  for (int it = 0; it < 4; ++it) {
    int f4i = it * 64 + lane;
    int c0 = f4i * 4;
    float v[4];
    v[0] = (c0 + 0 == id) ? 1.0f : 0.0f;
    v[1] = (c0 + 1 == id) ? 1.0f : 0.0f;
    v[2] = (c0 + 2 == id) ? 1.0f : 0.0f;
    v[3] = (c0 + 3 == id) ? 1.0f : 0.0f;
    __builtin_memcpy(ohb + (size_t)f4i * 4, v, 16);
  }

  #pragma unroll
  for (int off = 32; off; off >>= 1) lsum += __shfl_down(lsum, off, 64);
  __shared__ double lred[4];
  if (lane == 0) lred[tl] = lsum;
  __syncthreads();
  if (t == 0)
    unsafeAtomicAdd(&lossacc[blockIdx.x & 255],
                    lred[0] + lred[1] + lred[2] + lred[3]);
}

// ------------------------------------------------ histogram (LDS-privatized)
__global__ __launch_bounds__(256) void hist_k(const int* __restrict__ idxw,
                                              int* __restrict__ counts) {
  __shared__ int lc[NE];
  for (int i = threadIdx.x; i < NE; i += 256) lc[i] = 0;
  __syncthreads();
  const int stride = gridDim.x * 256;
  for (int i = blockIdx.x * 256 + threadIdx.x; i < NT; i += stride)
    atomicAdd(&lc[idxw[i]], 1);
  __syncthreads();
  for (int i = threadIdx.x; i < NE; i += 256) {
    int v = lc[i];
    if (v) atomicAdd(&counts[i], v);
  }
}

// ------------------------------- exclusive prefix sum (wave-parallel, exact)
__global__ __launch_bounds__(256) void scan_k(const int* __restrict__ counts,
                                              int* __restrict__ offsets) {
  const int t = threadIdx.x;            // 256 threads, 4 codes each
  const int lane = t & 63, w = t >> 6;
  int4 c = ((const int4*)counts)[t];
  int s = c.x + c.y + c.z + c.w;
  int v = s;                            // inclusive wave scan
  #pragma unroll
  for (int off = 1; off < 64; off <<= 1) {
    int u = __shfl_up(v, off, 64);
    if (lane >= off) v += u;
  }
  __shared__ int wsum[4];
  if (lane == 63) wsum[w] = v;
  __syncthreads();
  int base = 0;
  #pragma unroll
  for (int i = 0; i < 4; ++i) if (i < w) base += wsum[i];
  int excl = base + v - s;              // exclusive prefix of this thread
  int4 o;
  o.x = excl;
  o.y = o.x + c.x;
  o.z = o.y + c.y;
  o.w = o.z + c.z;
  ((int4*)offsets)[t] = o;
}

// -------------------------------------------------- scatter tokens into buckets
__global__ __launch_bounds__(256) void scatter_k(
    const int* __restrict__ idxw, const int* __restrict__ offsets,
    int* __restrict__ cursor, int* __restrict__ bucket,
    float* __restrict__ out) {
  int i = blockIdx.x * 256 + threadIdx.x;
  int id = idxw[i];
  out[OFF_IDX + i] = (float)id;
  int pos = atomicAdd(&cursor[id], 1);
  bucket[offsets[id] + pos] = i;
}

// ------------------- per-code segment sum (no atomics) fused with EMA update
__global__ __launch_bounds__(256) void segsum_k(
    const float* __restrict__ z, const float* __restrict__ nmat,
    const float* __restrict__ mmat, const int* __restrict__ counts,
    const int* __restrict__ offsets, const int* __restrict__ bucket,
    float* __restrict__ out) {
  const int j = blockIdx.x, t = threadIdx.x;
  const int cnt = counts[j], off = offsets[j];
  float s = 0.f;
  int i = 0;
  for (; i + 4 <= cnt; i += 4) {
    int t0 = bucket[off + i + 0], t1 = bucket[off + i + 1];
    int t2 = bucket[off + i + 2], t3 = bucket[off + i + 3];
    float a = z[(size_t)t0 * ED + t];
    float b = z[(size_t)t1 * ED + t];
    float c = z[(size_t)t2 * ED + t];
    float d = z[(size_t)t3 * ED + t];
    s += a; s += b; s += c; s += d;
  }
  for (; i < cnt; ++i) s += z[(size_t)bucket[off + i] * ED + t];

  float newn = nmat[j] * 0.99f + (float)cnt * 0.01f;
  if (t == 0) out[OFF_NN + j] = newn;
  const size_t o = (size_t)j * ED + t;
  float newm = 0.99f * mmat[o] + 0.01f * s;
  out[OFF_NM + o]   = newm;
  out[OFF_NEMB + o] = newm / newn;
}

// ------------------------------------------------------- scalar finalizers
__global__ __launch_bounds__(256) void scalars_k(
    const double* __restrict__ lossacc, const int* __restrict__ counts,
    float* __restrict__ out) {
  const int t = threadIdx.x;
  double lsum = lossacc[t];
  double h = 0.0;
  for (int c = t; c < NE; c += 256) {
    double e = (double)counts[c] / (double)NT;
    h += e * log(e + 1e-10);
  }
  #pragma unroll
  for (int off = 32; off; off >>= 1) {
    lsum += __shfl_down(lsum, off, 64);
    h    += __shfl_down(h,    off, 64);
  }
  __shared__ double sl[4], sh[4];
  if ((t & 63) == 0) { sl[t >> 6] = lsum; sh[t >> 6] = h; }
  __syncthreads();
  if (t == 0) {
    double mean = (sl[0] + sl[1] + sl[2] + sl[3]) / (double)((size_t)NT * ED);
    out[OFF_QL]  = (float)mean;
    out[OFF_CL]  = (float)(0.25 * mean);
    out[OFF_PPL] = (float)exp(-(sh[0] + sh[1] + sh[2] + sh[3]));
  }
}

// ------------------------------------------------------------------ launch
extern "C" void kernel_launch(void* const* d_in, const int* in_sizes, int n_in,
                              void* d_out, int out_size, void* d_ws, size_t ws_size,
                              hipStream_t stream) {
  const float* z    = (const float*)d_in[0];
  const float* emb  = (const float*)d_in[1];
  const float* nmat = (const float*)d_in[2];
  const float* mmat = (const float*)d_in[3];
  float* out = (float*)d_out;
  char*  ws  = (char*)d_ws;

  // ws layout (byte offsets):
  //   0       lossacc  double[256]  (2 KB)
  //   2048    nflag    int (zeroed by memset)
  //   4096    counts   int[1024]
  //   8192    cursor   int[1024]
  //   12288   offsets  int[1024]
  //   16384   bucket   int[131072]  (512 KB)
  //   540672  idxw     int[131072]  (512 KB)
  //   1064960 znorm    float[131072] (512 KB)
  //   1589248 enorm    float[1024]  (4 KB)
  //   1593344 eswz     f16 swizzled tiles (512 KB)
  //   2117632 flaglist int[131072]  (512 KB)
  double* lossacc = (double*)ws;
  int*    nflag   = (int*)(ws + 2048);
  int*    counts  = (int*)(ws + 4096);
  int*    cursor  = (int*)(ws + 8192);
  int*    offsets = (int*)(ws + 12288);
  int*    bucket  = (int*)(ws + 16384);
  int*    idxw    = (int*)(ws + 540672);
  float*  znorm   = (float*)(ws + 1064960);
  float*  enorm   = (float*)(ws + 1589248);
  char*   eswz    = ws + 1593344;
  int*    flaglist= (int*)(ws + 2117632);

  hipMemsetAsync(ws, 0, 12288, stream);  // lossacc + nflag + counts + cursor

  hipLaunchKernelGGL(rownorm_k, dim3(NT / 4), dim3(256), 0, stream, z, znorm, NT);
  hipLaunchKernelGGL(rownorm_k, dim3(NE / 4), dim3(256), 0, stream, emb, enorm, NE);
  hipLaunchKernelGGL(eprep_k, dim3(NE / 8), dim3(256), 0, stream, emb, eswz);
  hipLaunchKernelGGL(argmin_coarse_k, dim3(NT / 128), dim3(256), 0, stream,
                     z, eswz, enorm, idxw, nflag, flaglist);
  hipLaunchKernelGGL(argmin_refine_k, dim3(NT / 16), dim3(256), 0, stream,
                     z, emb, znorm, enorm, nflag, flaglist, idxw);
  hipLaunchKernelGGL(zq_oh_k, dim3(NT / 4), dim3(256), 0, stream,
                     z, emb, idxw, out, lossacc);
  hipLaunchKernelGGL(hist_k, dim3(64), dim3(256), 0, stream, idxw, counts);
  hipLaunchKernelGGL(scan_k, dim3(1), dim3(256), 0, stream, counts, offsets);
  hipLaunchKernelGGL(scatter_k, dim3(NT / 256), dim3(256), 0, stream,
                     idxw, offsets, cursor, bucket, out);
  hipLaunchKernelGGL(segsum_k, dim3(NE), dim3(256), 0, stream,
                     z, nmat, mmat, counts, offsets, bucket, out);
  hipLaunchKernelGGL(scalars_k, dim3(1), dim3(256), 0, stream,
                     lossacc, counts, out);
}

// Round 5
// 1258.859 us; speedup vs baseline: 1.1143x; 1.1143x over previous
//
#include <hip/hip_runtime.h>

// VQ-VAE vector quantizer step on MI355X (gfx950).
// Round 7: coarse argmin with async double-buffered LDS staging.
//   - argmin_coarse_k: global_load_lds(width=16) stages tile ct+1 into
//     LDS buf^1 BEFORE computing tile ct from buf; ONE __syncthreads per
//     tile (its implicit vmcnt(0) drain lands after ~600cyc of compute,
//     hiding L2 latency). Reads byte-identical fragment values to the
//     round-5 passing kernel -> identical numerics, identical flags.
//   - R4's global-B read path reverted (L1 line-throughput bound, -92us).
// All other kernels byte-identical to the round-6 version (parallel scan).

#define NT 131072   // tokens
#define NE 1024     // codebook entries
#define ED 256      // embedding dim

typedef _Float16 f16;
typedef f16  f16x8 __attribute__((ext_vector_type(8)));
typedef float f32x4 __attribute__((ext_vector_type(4)));

// Output layout (flat f32, reference return order)
static const size_t OFF_QL   = 0;            // quant_loss (1)
static const size_t OFF_CL   = 1;            // commit_loss (1)
static const size_t OFF_ZQ   = 2;            // z_q_st (131072*256)
static const size_t OFF_PPL  = 33554434ULL;  // perplexity (1)
static const size_t OFF_OH   = 33554435ULL;  // min_encodings (131072*1024)
static const size_t OFF_IDX  = 167772163ULL; // idx (131072)
static const size_t OFF_NEMB = 167903235ULL; // new_emb_weight (1024*256)
static const size_t OFF_NN   = 168165379ULL; // new_n_mat (1024)
static const size_t OFF_NM   = 168166403ULL; // new_m_mat (1024*256)

// async global->LDS, 16B per lane per call (1 KB per wave-call)
__device__ __forceinline__ void gload_lds16(const void* g, void* l) {
  __builtin_amdgcn_global_load_lds(
      (const __attribute__((address_space(1))) unsigned int*)g,
      (__attribute__((address_space(3))) unsigned int*)l, 16, 0, 0);
}

// ---------------------------------------------------------------- row norms
__global__ __launch_bounds__(256) void rownorm_k(const float* __restrict__ x,
                                                 float* __restrict__ o, int nrows) {
  int wid  = blockIdx.x * 4 + (threadIdx.x >> 6);  // one wave per row
  int lane = threadIdx.x & 63;
  if (wid >= nrows) return;
  float4 v = ((const float4*)(x + (size_t)wid * ED))[lane];
  float s = v.x * v.x + v.y * v.y + v.z * v.z + v.w * v.w;
  #pragma unroll
  for (int off = 32; off; off >>= 1) s += __shfl_down(s, off, 64);
  if (lane == 0) o[wid] = s;
}

// ------------------------------------- codebook prep: f16 (e*1024) swizzled
// Tile t (32 codes) = contiguous 16 KB block; 16B unit
// g = (c_local<<5) | (kq ^ (c_local&7)) holds e[c][8*kq .. 8*kq+8).
__global__ __launch_bounds__(256) void eprep_k(const float* __restrict__ emb,
                                               char* __restrict__ eswz) {
  const int t  = threadIdx.x;
  const int c  = blockIdx.x * 8 + (t >> 5);   // code
  const int kq = t & 31;                      // 8-elem unit within row
  const float* er = emb + (size_t)c * ED + kq * 8;
  float4 v0 = ((const float4*)er)[0];
  float4 v1 = ((const float4*)er)[1];
  float vv[8] = {v0.x, v0.y, v0.z, v0.w, v1.x, v1.y, v1.z, v1.w};
  f16x8 h;
  #pragma unroll
  for (int i = 0; i < 8; ++i) h[i] = (f16)(vv[i] * 1024.0f);  // exact pow2 scale
  const int tile = c >> 5, cl = c & 31;
  const int g = (cl << 5) | (kq ^ (cl & 7));
  *(f16x8*)(eswz + (size_t)tile * 16384 + (size_t)g * 16) = h;
}

// --------------------------------------------- coarse MFMA distance argmin
// dd_j = ||e_j||^2 - 2 z.e_j  (token-invariant ||z||^2 dropped).
// Double-buffered LDS; stage(ct+1) issued before compute(ct); one barrier
// per tile drains vmcnt after compute has covered the latency.
__global__ __launch_bounds__(256, 2) void argmin_coarse_k(
    const float* __restrict__ z, const char* __restrict__ eswz,
    const float* __restrict__ enorm, int* __restrict__ idxw,
    int* __restrict__ nflag, int* __restrict__ flaglist) {
  __shared__ uint4 ebuf[2][1024];                 // 2 x 16 KB

  const int tid  = threadIdx.x;
  const int w    = tid >> 6, lane = tid & 63;
  const int lr   = lane & 15, kg = lane >> 4;
  const int r0   = blockIdx.x * 128 + w * 32;

  // A fragments: row = lane&15, k = kt*32 + kg*8 + i  (validated rounds 2/5)
  f16x8 ah[2][8];
  #pragma unroll
  for (int mf = 0; mf < 2; ++mf) {
    const float* zr = z + (size_t)(r0 + mf * 16 + lr) * ED + kg * 8;
    #pragma unroll
    for (int kt = 0; kt < 8; ++kt) {
      float4 a = ((const float4*)(zr + kt * 32))[0];
      float4 b = ((const float4*)(zr + kt * 32))[1];
      float vv[8] = {a.x, a.y, a.z, a.w, b.x, b.y, b.z, b.w};
      #pragma unroll
      for (int i = 0; i < 8; ++i) ah[mf][kt][i] = (f16)vv[i];
    }
  }

  float m1[2][4], m2[2][4]; int i1[2][4];
  #pragma unroll
  for (int mf = 0; mf < 2; ++mf)
    #pragma unroll
    for (int r = 0; r < 4; ++r) {
      m1[mf][r] = 3.4028235e38f; m2[mf][r] = 3.4028235e38f; i1[mf][r] = 0;
    }

  const int soff = w * 4096 + lane * 16;          // this lane's stage slot
  // prologue: stage tile 0 into buf 0
  #pragma unroll
  for (int c = 0; c < 4; ++c)
    gload_lds16(eswz + soff + c * 1024,
                (char*)ebuf[0] + w * 4096 + c * 1024);
  __syncthreads();                                // drains stage(0)

  for (int ct = 0; ct < 32; ++ct) {
    const int cur = ct & 1;
    if (ct < 31) {                                // stage next tile (async)
      const char* ntb = eswz + (size_t)(ct + 1) * 16384 + soff;
      #pragma unroll
      for (int c = 0; c < 4; ++c)
        gload_lds16(ntb + c * 1024,
                    (char*)ebuf[cur ^ 1] + w * 4096 + c * 1024);
    }
    const char* eb = (const char*)ebuf[cur];

    f32x4 acc[2][2];
    #pragma unroll
    for (int mf = 0; mf < 2; ++mf)
      #pragma unroll
      for (int nf = 0; nf < 2; ++nf) acc[mf][nf] = (f32x4){0.f, 0.f, 0.f, 0.f};

    #pragma unroll
    for (int kt = 0; kt < 8; ++kt) {
      f16x8 b0, b1;
      #pragma unroll
      for (int nf = 0; nf < 2; ++nf) {
        const int cl = nf * 16 + lr;
        const int kq = kt * 4 + kg;
        const int u  = (cl << 5) | (kq ^ (cl & 7));
        f16x8 bv = *(const f16x8*)(eb + u * 16);
        if (nf == 0) b0 = bv; else b1 = bv;
      }
      acc[0][0] = __builtin_amdgcn_mfma_f32_16x16x32_f16(ah[0][kt], b0, acc[0][0], 0, 0, 0);
      acc[1][0] = __builtin_amdgcn_mfma_f32_16x16x32_f16(ah[1][kt], b0, acc[1][0], 0, 0, 0);
      acc[0][1] = __builtin_amdgcn_mfma_f32_16x16x32_f16(ah[0][kt], b1, acc[0][1], 0, 0, 0);
      acc[1][1] = __builtin_amdgcn_mfma_f32_16x16x32_f16(ah[1][kt], b1, acc[1][1], 0, 0, 0);
    }

    // C/D: col = lane&15, row = kg*4 + r
    #pragma unroll
    for (int nf = 0; nf < 2; ++nf) {
      const int c = ct * 32 + nf * 16 + lr;
      const float en = enorm[c];
      #pragma unroll
      for (int mf = 0; mf < 2; ++mf)
        #pragma unroll
        for (int r = 0; r < 4; ++r) {
          float dd = en - 0.001953125f * acc[mf][nf][r];   // en - 2*dot
          if (dd < m1[mf][r]) {
            m2[mf][r] = m1[mf][r]; m1[mf][r] = dd; i1[mf][r] = c;
          } else if (dd < m2[mf][r]) {
            m2[mf][r] = dd;
          }
        }
    }
    __syncthreads();   // readers of buf[cur] done; drains stage(ct+1)
  }

  // reduce (min1,min2) across the 16 column-lanes (lane bits 0..3)
  #pragma unroll
  for (int mf = 0; mf < 2; ++mf)
    #pragma unroll
    for (int r = 0; r < 4; ++r) {
      float a1 = m1[mf][r]; int ai = i1[mf][r]; float a2 = m2[mf][r];
      #pragma unroll
      for (int off = 1; off < 16; off <<= 1) {
        float o1 = __shfl_xor(a1, off, 64);
        int   oi = __shfl_xor(ai, off, 64);
        float o2 = __shfl_xor(a2, off, 64);
        if (o1 < a1) { a2 = fminf(a1, o2); a1 = o1; ai = oi; }
        else         { a2 = fminf(a2, o1); }
      }
      if (lr == 0) {
        const int row = r0 + mf * 16 + kg * 4 + r;
        idxw[row] = ai;                          // provisional if flagged
        if (a2 - a1 < 4.0e-4f) {
          int p = atomicAdd(nflag, 1);
          flaglist[p] = row;
        }
      }
    }
}

// ------------------------- exact fp32 refine (round-1 arithmetic) for flags
__global__ __launch_bounds__(256) void argmin_refine_k(
    const float* __restrict__ z, const float* __restrict__ emb,
    const float* __restrict__ znorm, const float* __restrict__ enorm,
    const int* __restrict__ nflag, const int* __restrict__ flaglist,
    int* __restrict__ idxw) {
  const int nf = *nflag;
  const int b0 = blockIdx.x * 16;
  if (b0 >= nf) return;

  __shared__ float zl[16][256];    // 16 KB staged z rows
  __shared__ int   toks[16];
  __shared__ float rv[4][16];
  __shared__ int   ri[4][16];

  const int t = threadIdx.x;
  if (t < 16) {
    int li = b0 + t;
    toks[t] = flaglist[li < nf ? li : b0];   // tail clamps to a valid token
  }
  __syncthreads();

  #pragma unroll
  for (int i = 0; i < 4; ++i) {
    int li = t + i * 256;                    // 0..1023 float4 units
    int row = li >> 6, c4 = li & 63;
    float4 v = ((const float4*)(z + (size_t)toks[row] * ED))[c4];
    *(float4*)&zl[row][c4 * 4] = v;
  }
  __syncthreads();

  float acc[4][16];
  #pragma unroll
  for (int cc = 0; cc < 4; ++cc)
    #pragma unroll
    for (int tk = 0; tk < 16; ++tk) acc[cc][tk] = 0.f;

  for (int c4 = 0; c4 < 64; ++c4) {
    float4 e[4];
    #pragma unroll
    for (int cc = 0; cc < 4; ++cc)
      e[cc] = ((const float4*)(emb + (size_t)(t * 4 + cc) * ED))[c4];
    #pragma unroll
    for (int tk = 0; tk < 16; ++tk) {
      float4 zv = *(const float4*)&zl[tk][c4 * 4];
      #pragma unroll
      for (int cc = 0; cc < 4; ++cc) {
        acc[cc][tk] += zv.x * e[cc].x;
        acc[cc][tk] += zv.y * e[cc].y;
        acc[cc][tk] += zv.z * e[cc].z;
        acc[cc][tk] += zv.w * e[cc].w;
      }
    }
  }

  float en[4];
  #pragma unroll
  for (int cc = 0; cc < 4; ++cc) en[cc] = enorm[t * 4 + cc];

  const int wv = t >> 6, lane = t & 63;
  for (int tk = 0; tk < 16; ++tk) {
    const float zn = znorm[toks[tk]];
    float bv = 3.4028235e38f; int bi = 0;
    #pragma unroll
    for (int cc = 0; cc < 4; ++cc) {
      float s = zn + en[cc];                  // exact round-1 expression
      float d = s - 2.0f * acc[cc][tk];
      int   c = t * 4 + cc;
      if (d < bv) { bv = d; bi = c; }
    }
    #pragma unroll
    for (int off = 32; off; off >>= 1) {
      float ov = __shfl_down(bv, off, 64);
      int   oi = __shfl_down(bi, off, 64);
      if (ov < bv || (ov == bv && oi < bi)) { bv = ov; bi = oi; }
    }
    if (lane == 0) { rv[wv][tk] = bv; ri[wv][tk] = bi; }
  }
  __syncthreads();
  if (t < 16) {
    float bv = rv[0][t]; int bi = ri[0][t];
    #pragma unroll
    for (int wq = 1; wq < 4; ++wq) {
      float ov = rv[wq][t]; int oi = ri[wq][t];
      if (ov < bv || (ov == bv && oi < bi)) { bv = ov; bi = oi; }
    }
    idxw[toks[t]] = bi;
  }
}

// ------------------------- streaming per-token outputs: z_q, one-hot, loss
__global__ __launch_bounds__(256) void zq_oh_k(
    const float* __restrict__ z, const float* __restrict__ emb,
    const int* __restrict__ idxw, float* __restrict__ out,
    double* __restrict__ lossacc) {
  const int t = threadIdx.x;
  const int tl = t >> 6, lane = t & 63;
  const int tok = blockIdx.x * 4 + tl;
  const int id = idxw[tok];

  float4 z4 = ((const float4*)(z   + (size_t)tok * ED))[lane];
  float4 e4 = ((const float4*)(emb + (size_t)id  * ED))[lane];
  float4 q;
  q.x = z4.x + (e4.x - z4.x);   // straight-through, exact ref formula
  q.y = z4.y + (e4.y - z4.y);
  q.z = z4.z + (e4.z - z4.z);
  q.w = z4.w + (e4.w - z4.w);
  __builtin_memcpy(out + OFF_ZQ + (size_t)tok * ED + (size_t)lane * 4, &q, 16);

  float dx = e4.x - z4.x, dy = e4.y - z4.y, dz = e4.z - z4.z, dw = e4.w - z4.w;
  double lsum = (double)(dx * dx) + (double)(dy * dy)
              + (double)(dz * dz) + (double)(dw * dw);

  float* ohb = out + OFF_OH + (size_t)tok * NE;
  #pragma unroll
  for (int it = 0; it < 4; ++it) {
    int f4i = it * 64 + lane;
    int c0 = f4i * 4;
    float v[4];
    v[0] = (c0 + 0 == id) ? 1.0f : 0.0f;
    v[1] = (c0 + 1 == id) ? 1.0f : 0.0f;
    v[2] = (c0 + 2 == id) ? 1.0f : 0.0f;
    v[3] = (c0 + 3 == id) ? 1.0f : 0.0f;
    __builtin_memcpy(ohb + (size_t)f4i * 4, v, 16);
  }

  #pragma unroll
  for (int off = 32; off; off >>= 1) lsum += __shfl_down(lsum, off, 64);
  __shared__ double lred[4];
  if (lane == 0) lred[tl] = lsum;
  __syncthreads();
  if (t == 0)
    unsafeAtomicAdd(&lossacc[blockIdx.x & 255],
                    lred[0] + lred[1] + lred[2] + lred[3]);
}

// ------------------------------------------------ histogram (LDS-privatized)
__global__ __launch_bounds__(256) void hist_k(const int* __restrict__ idxw,
                                              int* __restrict__ counts) {
  __shared__ int lc[NE];
  for (int i = threadIdx.x; i < NE; i += 256) lc[i] = 0;
  __syncthreads();
  const int stride = gridDim.x * 256;
  for (int i = blockIdx.x * 256 + threadIdx.x; i < NT; i += stride)
    atomicAdd(&lc[idxw[i]], 1);
  __syncthreads();
  for (int i = threadIdx.x; i < NE; i += 256) {
    int v = lc[i];
    if (v) atomicAdd(&counts[i], v);
  }
}

// ------------------------------- exclusive prefix sum (wave-parallel, exact)
__global__ __launch_bounds__(256) void scan_k(const int* __restrict__ counts,
                                              int* __restrict__ offsets) {
  const int t = threadIdx.x;            // 256 threads, 4 codes each
  const int lane = t & 63, w = t >> 6;
  int4 c = ((const int4*)counts)[t];
  int s = c.x + c.y + c.z + c.w;
  int v = s;                            // inclusive wave scan
  #pragma unroll
  for (int off = 1; off < 64; off <<= 1) {
    int u = __shfl_up(v, off, 64);
    if (lane >= off) v += u;
  }
  __shared__ int wsum[4];
  if (lane == 63) wsum[w] = v;
  __syncthreads();
  int base = 0;
  #pragma unroll
  for (int i = 0; i < 4; ++i) if (i < w) base += wsum[i];
  int excl = base + v - s;              // exclusive prefix of this thread
  int4 o;
  o.x = excl;
  o.y = o.x + c.x;
  o.z = o.y + c.y;
  o.w = o.z + c.z;
  ((int4*)offsets)[t] = o;
}

// -------------------------------------------------- scatter tokens into buckets
__global__ __launch_bounds__(256) void scatter_k(
    const int* __restrict__ idxw, const int* __restrict__ offsets,
    int* __restrict__ cursor, int* __restrict__ bucket,
    float* __restrict__ out) {
  int i = blockIdx.x * 256 + threadIdx.x;
  int id = idxw[i];
  out[OFF_IDX + i] = (float)id;
  int pos = atomicAdd(&cursor[id], 1);
  bucket[offsets[id] + pos] = i;
}

// ------------------- per-code segment sum (no atomics) fused with EMA update
__global__ __launch_bounds__(256) void segsum_k(
    const float* __restrict__ z, const float* __restrict__ nmat,
    const float* __restrict__ mmat, const int* __restrict__ counts,
    const int* __restrict__ offsets, const int* __restrict__ bucket,
    float* __restrict__ out) {
  const int j = blockIdx.x, t = threadIdx.x;
  const int cnt = counts[j], off = offsets[j];
  float s = 0.f;
  int i = 0;
  for (; i + 4 <= cnt; i += 4) {
    int t0 = bucket[off + i + 0], t1 = bucket[off + i + 1];
    int t2 = bucket[off + i + 2], t3 = bucket[off + i + 3];
    float a = z[(size_t)t0 * ED + t];
    float b = z[(size_t)t1 * ED + t];
    float c = z[(size_t)t2 * ED + t];
    float d = z[(size_t)t3 * ED + t];
    s += a; s += b; s += c; s += d;
  }
  for (; i < cnt; ++i) s += z[(size_t)bucket[off + i] * ED + t];

  float newn = nmat[j] * 0.99f + (float)cnt * 0.01f;
  if (t == 0) out[OFF_NN + j] = newn;
  const size_t o = (size_t)j * ED + t;
  float newm = 0.99f * mmat[o] + 0.01f * s;
  out[OFF_NM + o]   = newm;
  out[OFF_NEMB + o] = newm / newn;
}

// ------------------------------------------------------- scalar finalizers
__global__ __launch_bounds__(256) void scalars_k(
    const double* __restrict__ lossacc, const int* __restrict__ counts,
    float* __restrict__ out) {
  const int t = threadIdx.x;
  double lsum = lossacc[t];
  double h = 0.0;
  for (int c = t; c < NE; c += 256) {
    double e = (double)counts[c] / (double)NT;
    h += e * log(e + 1e-10);
  }
  #pragma unroll
  for (int off = 32; off; off >>= 1) {
    lsum += __shfl_down(lsum, off, 64);
    h    += __shfl_down(h,    off, 64);
  }
  __shared__ double sl[4], sh[4];
  if ((t & 63) == 0) { sl[t >> 6] = lsum; sh[t >> 6] = h; }
  __syncthreads();
  if (t == 0) {
    double mean = (sl[0] + sl[1] + sl[2] + sl[3]) / (double)((size_t)NT * ED);
    out[OFF_QL]  = (float)mean;
    out[OFF_CL]  = (float)(0.25 * mean);
    out[OFF_PPL] = (float)exp(-(sh[0] + sh[1] + sh[2] + sh[3]));
  }
}

// ------------------------------------------------------------------ launch
extern "C" void kernel_launch(void* const* d_in, const int* in_sizes, int n_in,
                              void* d_out, int out_size, void* d_ws, size_t ws_size,
                              hipStream_t stream) {
  const float* z    = (const float*)d_in[0];
  const float* emb  = (const float*)d_in[1];
  const float* nmat = (const float*)d_in[2];
  const float* mmat = (const float*)d_in[3];
  float* out = (float*)d_out;
  char*  ws  = (char*)d_ws;

  // ws layout (byte offsets):
  //   0       lossacc  double[256]  (2 KB)
  //   2048    nflag    int (zeroed by memset)
  //   4096    counts   int[1024]
  //   8192    cursor   int[1024]
  //   12288   offsets  int[1024]
  //   16384   bucket   int[131072]  (512 KB)
  //   540672  idxw     int[131072]  (512 KB)
  //   1064960 znorm    float[131072] (512 KB)
  //   1589248 enorm    float[1024]  (4 KB)
  //   1593344 eswz     f16 swizzled tiles (512 KB)
  //   2117632 flaglist int[131072]  (512 KB)
  double* lossacc = (double*)ws;
  int*    nflag   = (int*)(ws + 2048);
  int*    counts  = (int*)(ws + 4096);
  int*    cursor  = (int*)(ws + 8192);
  int*    offsets = (int*)(ws + 12288);
  int*    bucket  = (int*)(ws + 16384);
  int*    idxw    = (int*)(ws + 540672);
  float*  znorm   = (float*)(ws + 1064960);
  float*  enorm   = (float*)(ws + 1589248);
  char*   eswz    = ws + 1593344;
  int*    flaglist= (int*)(ws + 2117632);

  hipMemsetAsync(ws, 0, 12288, stream);  // lossacc + nflag + counts + cursor

  hipLaunchKernelGGL(rownorm_k, dim3(NT / 4), dim3(256), 0, stream, z, znorm, NT);
  hipLaunchKernelGGL(rownorm_k, dim3(NE / 4), dim3(256), 0, stream, emb, enorm, NE);
  hipLaunchKernelGGL(eprep_k, dim3(NE / 8), dim3(256), 0, stream, emb, eswz);
  hipLaunchKernelGGL(argmin_coarse_k, dim3(NT / 128), dim3(256), 0, stream,
                     z, eswz, enorm, idxw, nflag, flaglist);
  hipLaunchKernelGGL(argmin_refine_k, dim3(NT / 16), dim3(256), 0, stream,
                     z, emb, znorm, enorm, nflag, flaglist, idxw);
  hipLaunchKernelGGL(zq_oh_k, dim3(NT / 4), dim3(256), 0, stream,
                     z, emb, idxw, out, lossacc);
  hipLaunchKernelGGL(hist_k, dim3(64), dim3(256), 0, stream, idxw, counts);
  hipLaunchKernelGGL(scan_k, dim3(1), dim3(256), 0, stream, counts, offsets);
  hipLaunchKernelGGL(scatter_k, dim3(NT / 256), dim3(256), 0, stream,
                     idxw, offsets, cursor, bucket, out);
  hipLaunchKernelGGL(segsum_k, dim3(NE), dim3(256), 0, stream,
                     z, nmat, mmat, counts, offsets, bucket, out);
  hipLaunchKernelGGL(scalars_k, dim3(1), dim3(256), 0, stream,
                     lossacc, counts, out);
}

// Round 6
// 1235.800 us; speedup vs baseline: 1.1351x; 1.0187x over previous
//
#include <hip/hip_runtime.h>

// VQ-VAE vector quantizer step on MI355X (gfx950).
// Round 8: spill fix + atomic batching + aligned store streams.
//   - argmin_coarse_k: __launch_bounds__(256,1) (was (256,2) -> 128-VGPR cap
//     with ~150 live regs => inner-loop scratch spills, the 4-5x mystery).
//     Flags batched per-block in LDS -> one global atomic per block.
//   - zq_oh_k: all global stores 16B-aligned (ZQ via 2-float lane rotation,
//     OH via aligned body + head/tail scalars). Values identical.
// refine/hist/scan/scatter/segsum/scalars byte-identical to round 7.

#define NT 131072   // tokens
#define NE 1024     // codebook entries
#define ED 256      // embedding dim

typedef _Float16 f16;
typedef f16  f16x8 __attribute__((ext_vector_type(8)));
typedef float f32x4 __attribute__((ext_vector_type(4)));

// Output layout (flat f32, reference return order)
static const size_t OFF_QL   = 0;            // quant_loss (1)
static const size_t OFF_CL   = 1;            // commit_loss (1)
static const size_t OFF_ZQ   = 2;            // z_q_st (131072*256)
static const size_t OFF_PPL  = 33554434ULL;  // perplexity (1)
static const size_t OFF_OH   = 33554435ULL;  // min_encodings (131072*1024)
static const size_t OFF_IDX  = 167772163ULL; // idx (131072)
static const size_t OFF_NEMB = 167903235ULL; // new_emb_weight (1024*256)
static const size_t OFF_NN   = 168165379ULL; // new_n_mat (1024)
static const size_t OFF_NM   = 168166403ULL; // new_m_mat (1024*256)

// async global->LDS, 16B per lane per call (1 KB per wave-call)
__device__ __forceinline__ void gload_lds16(const void* g, void* l) {
  __builtin_amdgcn_global_load_lds(
      (const __attribute__((address_space(1))) unsigned int*)g,
      (__attribute__((address_space(3))) unsigned int*)l, 16, 0, 0);
}

// ---------------------------------------------------------------- row norms
__global__ __launch_bounds__(256) void rownorm_k(const float* __restrict__ x,
                                                 float* __restrict__ o, int nrows) {
  int wid  = blockIdx.x * 4 + (threadIdx.x >> 6);  // one wave per row
  int lane = threadIdx.x & 63;
  if (wid >= nrows) return;
  float4 v = ((const float4*)(x + (size_t)wid * ED))[lane];
  float s = v.x * v.x + v.y * v.y + v.z * v.z + v.w * v.w;
  #pragma unroll
  for (int off = 32; off; off >>= 1) s += __shfl_down(s, off, 64);
  if (lane == 0) o[wid] = s;
}

// ------------------------------------- codebook prep: f16 (e*1024) swizzled
// Tile t (32 codes) = contiguous 16 KB block; 16B unit
// g = (c_local<<5) | (kq ^ (c_local&7)) holds e[c][8*kq .. 8*kq+8).
__global__ __launch_bounds__(256) void eprep_k(const float* __restrict__ emb,
                                               char* __restrict__ eswz) {
  const int t  = threadIdx.x;
  const int c  = blockIdx.x * 8 + (t >> 5);   // code
  const int kq = t & 31;                      // 8-elem unit within row
  const float* er = emb + (size_t)c * ED + kq * 8;
  float4 v0 = ((const float4*)er)[0];
  float4 v1 = ((const float4*)er)[1];
  float vv[8] = {v0.x, v0.y, v0.z, v0.w, v1.x, v1.y, v1.z, v1.w};
  f16x8 h;
  #pragma unroll
  for (int i = 0; i < 8; ++i) h[i] = (f16)(vv[i] * 1024.0f);  // exact pow2 scale
  const int tile = c >> 5, cl = c & 31;
  const int g = (cl << 5) | (kq ^ (cl & 7));
  *(f16x8*)(eswz + (size_t)tile * 16384 + (size_t)g * 16) = h;
}

// --------------------------------------------- coarse MFMA distance argmin
// dd_j = ||e_j||^2 - 2 z.e_j  (token-invariant ||z||^2 dropped).
// Double-buffered async LDS staging; one barrier per tile.
// launch_bounds(256,1): no 128-VGPR cap (the kernel holds ~150 live regs;
// the old (256,2) cap forced inner-loop scratch spills). Occupancy stays
// 2 waves/SIMD (129-256 VGPR band).
__global__ __launch_bounds__(256, 1) void argmin_coarse_k(
    const float* __restrict__ z, const char* __restrict__ eswz,
    const float* __restrict__ enorm, int* __restrict__ idxw,
    int* __restrict__ nflag, int* __restrict__ flaglist) {
  __shared__ uint4 ebuf[2][1024];                 // 2 x 16 KB
  __shared__ int   fcnt, fbase;
  __shared__ int   frow[128];

  const int tid  = threadIdx.x;
  const int w    = tid >> 6, lane = tid & 63;
  const int lr   = lane & 15, kg = lane >> 4;
  const int r0   = blockIdx.x * 128 + w * 32;
  if (tid == 0) fcnt = 0;

  // A fragments: row = lane&15, k = kt*32 + kg*8 + i  (validated rounds 2/5)
  f16x8 ah[2][8];
  #pragma unroll
  for (int mf = 0; mf < 2; ++mf) {
    const float* zr = z + (size_t)(r0 + mf * 16 + lr) * ED + kg * 8;
    #pragma unroll
    for (int kt = 0; kt < 8; ++kt) {
      float4 a = ((const float4*)(zr + kt * 32))[0];
      float4 b = ((const float4*)(zr + kt * 32))[1];
      float vv[8] = {a.x, a.y, a.z, a.w, b.x, b.y, b.z, b.w};
      #pragma unroll
      for (int i = 0; i < 8; ++i) ah[mf][kt][i] = (f16)vv[i];
    }
  }

  float m1[2][4], m2[2][4]; int i1[2][4];
  #pragma unroll
  for (int mf = 0; mf < 2; ++mf)
    #pragma unroll
    for (int r = 0; r < 4; ++r) {
      m1[mf][r] = 3.4028235e38f; m2[mf][r] = 3.4028235e38f; i1[mf][r] = 0;
    }

  const int soff = w * 4096 + lane * 16;          // this lane's stage slot
  // prologue: stage tile 0 into buf 0
  #pragma unroll
  for (int c = 0; c < 4; ++c)
    gload_lds16(eswz + soff + c * 1024,
                (char*)ebuf[0] + w * 4096 + c * 1024);
  __syncthreads();                                // drains stage(0)

  for (int ct = 0; ct < 32; ++ct) {
    const int cur = ct & 1;
    if (ct < 31) {                                // stage next tile (async)
      const char* ntb = eswz + (size_t)(ct + 1) * 16384 + soff;
      #pragma unroll
      for (int c = 0; c < 4; ++c)
        gload_lds16(ntb + c * 1024,
                    (char*)ebuf[cur ^ 1] + w * 4096 + c * 1024);
    }
    const char* eb = (const char*)ebuf[cur];

    f32x4 acc[2][2];
    #pragma unroll
    for (int mf = 0; mf < 2; ++mf)
      #pragma unroll
      for (int nf = 0; nf < 2; ++nf) acc[mf][nf] = (f32x4){0.f, 0.f, 0.f, 0.f};

    #pragma unroll
    for (int kt = 0; kt < 8; ++kt) {
      f16x8 b0, b1;
      #pragma unroll
      for (int nf = 0; nf < 2; ++nf) {
        const int cl = nf * 16 + lr;
        const int kq = kt * 4 + kg;
        const int u  = (cl << 5) | (kq ^ (cl & 7));
        f16x8 bv = *(const f16x8*)(eb + u * 16);
        if (nf == 0) b0 = bv; else b1 = bv;
      }
      acc[0][0] = __builtin_amdgcn_mfma_f32_16x16x32_f16(ah[0][kt], b0, acc[0][0], 0, 0, 0);
      acc[1][0] = __builtin_amdgcn_mfma_f32_16x16x32_f16(ah[1][kt], b0, acc[1][0], 0, 0, 0);
      acc[0][1] = __builtin_amdgcn_mfma_f32_16x16x32_f16(ah[0][kt], b1, acc[0][1], 0, 0, 0);
      acc[1][1] = __builtin_amdgcn_mfma_f32_16x16x32_f16(ah[1][kt], b1, acc[1][1], 0, 0, 0);
    }

    // C/D: col = lane&15, row = kg*4 + r
    #pragma unroll
    for (int nf = 0; nf < 2; ++nf) {
      const int c = ct * 32 + nf * 16 + lr;
      const float en = enorm[c];
      #pragma unroll
      for (int mf = 0; mf < 2; ++mf)
        #pragma unroll
        for (int r = 0; r < 4; ++r) {
          float dd = en - 0.001953125f * acc[mf][nf][r];   // en - 2*dot
          if (dd < m1[mf][r]) {
            m2[mf][r] = m1[mf][r]; m1[mf][r] = dd; i1[mf][r] = c;
          } else if (dd < m2[mf][r]) {
            m2[mf][r] = dd;
          }
        }
    }
    __syncthreads();   // readers of buf[cur] done; drains stage(ct+1)
  }

  // reduce (min1,min2) across the 16 column-lanes (lane bits 0..3)
  #pragma unroll
  for (int mf = 0; mf < 2; ++mf)
    #pragma unroll
    for (int r = 0; r < 4; ++r) {
      float a1 = m1[mf][r]; int ai = i1[mf][r]; float a2 = m2[mf][r];
      #pragma unroll
      for (int off = 1; off < 16; off <<= 1) {
        float o1 = __shfl_xor(a1, off, 64);
        int   oi = __shfl_xor(ai, off, 64);
        float o2 = __shfl_xor(a2, off, 64);
        if (o1 < a1) { a2 = fminf(a1, o2); a1 = o1; ai = oi; }
        else         { a2 = fminf(a2, o1); }
      }
      if (lr == 0) {
        const int row = r0 + mf * 16 + kg * 4 + r;
        idxw[row] = ai;                          // provisional if flagged
        if (a2 - a1 < 4.0e-4f) {                 // near-tie: queue locally
          int p = atomicAdd(&fcnt, 1);
          frow[p] = row;
        }
      }
    }
  __syncthreads();
  if (tid == 0 && fcnt > 0) fbase = atomicAdd(nflag, fcnt);
  __syncthreads();
  for (int i = tid; i < fcnt; i += 256) flaglist[fbase + i] = frow[i];
}

// ------------------------- exact fp32 refine (round-1 arithmetic) for flags
__global__ __launch_bounds__(256) void argmin_refine_k(
    const float* __restrict__ z, const float* __restrict__ emb,
    const float* __restrict__ znorm, const float* __restrict__ enorm,
    const int* __restrict__ nflag, const int* __restrict__ flaglist,
    int* __restrict__ idxw) {
  const int nf = *nflag;
  const int b0 = blockIdx.x * 16;
  if (b0 >= nf) return;

  __shared__ float zl[16][256];    // 16 KB staged z rows
  __shared__ int   toks[16];
  __shared__ float rv[4][16];
  __shared__ int   ri[4][16];

  const int t = threadIdx.x;
  if (t < 16) {
    int li = b0 + t;
    toks[t] = flaglist[li < nf ? li : b0];   // tail clamps to a valid token
  }
  __syncthreads();

  #pragma unroll
  for (int i = 0; i < 4; ++i) {
    int li = t + i * 256;                    // 0..1023 float4 units
    int row = li >> 6, c4 = li & 63;
    float4 v = ((const float4*)(z + (size_t)toks[row] * ED))[c4];
    *(float4*)&zl[row][c4 * 4] = v;
  }
  __syncthreads();

  float acc[4][16];
  #pragma unroll
  for (int cc = 0; cc < 4; ++cc)
    #pragma unroll
    for (int tk = 0; tk < 16; ++tk) acc[cc][tk] = 0.f;

  for (int c4 = 0; c4 < 64; ++c4) {
    float4 e[4];
    #pragma unroll
    for (int cc = 0; cc < 4; ++cc)
      e[cc] = ((const float4*)(emb + (size_t)(t * 4 + cc) * ED))[c4];
    #pragma unroll
    for (int tk = 0; tk < 16; ++tk) {
      float4 zv = *(const float4*)&zl[tk][c4 * 4];
      #pragma unroll
      for (int cc = 0; cc < 4; ++cc) {
        acc[cc][tk] += zv.x * e[cc].x;
        acc[cc][tk] += zv.y * e[cc].y;
        acc[cc][tk] += zv.z * e[cc].z;
        acc[cc][tk] += zv.w * e[cc].w;
      }
    }
  }

  float en[4];
  #pragma unroll
  for (int cc = 0; cc < 4; ++cc) en[cc] = enorm[t * 4 + cc];

  const int wv = t >> 6, lane = t & 63;
  for (int tk = 0; tk < 16; ++tk) {
    const float zn = znorm[toks[tk]];
    float bv = 3.4028235e38f; int bi = 0;
    #pragma unroll
    for (int cc = 0; cc < 4; ++cc) {
      float s = zn + en[cc];                  // exact round-1 expression
      float d = s - 2.0f * acc[cc][tk];
      int   c = t * 4 + cc;
      if (d < bv) { bv = d; bi = c; }
    }
    #pragma unroll
    for (int off = 32; off; off >>= 1) {
      float ov = __shfl_down(bv, off, 64);
      int   oi = __shfl_down(bi, off, 64);
      if (ov < bv || (ov == bv && oi < bi)) { bv = ov; bi = oi; }
    }
    if (lane == 0) { rv[wv][tk] = bv; ri[wv][tk] = bi; }
  }
  __syncthreads();
  if (t < 16) {
    float bv = rv[0][t]; int bi = ri[0][t];
    #pragma unroll
    for (int wq = 1; wq < 4; ++wq) {
      float ov = rv[wq][t]; int oi = ri[wq][t];
      if (ov < bv || (ov == bv && oi < bi)) { bv = ov; bi = oi; }
    }
    idxw[toks[t]] = bi;
  }
}

// ------------------------- streaming per-token outputs: z_q, one-hot, loss
// All stores 16B-aligned: ZQ row (base==2 mod 4 floats) stored via 2-float
// lane rotation; OH row (base==3 mod 4) stored as head scalar + aligned
// float4 body + 3 tail scalars. Values bit-identical to round 7.
__global__ __launch_bounds__(256) void zq_oh_k(
    const float* __restrict__ z, const float* __restrict__ emb,
    const int* __restrict__ idxw, float* __restrict__ out,
    double* __restrict__ lossacc) {
  const int t = threadIdx.x;
  const int tl = t >> 6, lane = t & 63;
  const int tok = blockIdx.x * 4 + tl;
  const int id = idxw[tok];

  float4 z4 = ((const float4*)(z   + (size_t)tok * ED))[lane];
  float4 e4 = ((const float4*)(emb + (size_t)id  * ED))[lane];
  float4 q;
  q.x = z4.x + (e4.x - z4.x);   // straight-through, exact ref formula
  q.y = z4.y + (e4.y - z4.y);
  q.z = z4.z + (e4.z - z4.z);
  q.w = z4.w + (e4.w - z4.w);

  // ---- z_q aligned store via rotation: float4 i covers dims 2+4i..5+4i
  float* zb = out + OFF_ZQ + (size_t)tok * ED;
  float nx = __shfl_down(q.x, 1, 64);
  float ny = __shfl_down(q.y, 1, 64);
  if (lane == 0) { zb[0] = q.x; zb[1] = q.y; }
  if (lane < 63) {
    float4 sv; sv.x = q.z; sv.y = q.w; sv.z = nx; sv.w = ny;
    ((float4*)(zb + 2))[lane] = sv;            // zb+2 is 16B-aligned
  } else {
    zb[254] = q.z; zb[255] = q.w;
  }

  float dx = e4.x - z4.x, dy = e4.y - z4.y, dz = e4.z - z4.z, dw = e4.w - z4.w;
  double lsum = (double)(dx * dx) + (double)(dy * dy)
              + (double)(dz * dz) + (double)(dw * dw);

  // ---- one-hot aligned stores: head code 0, body codes 1..1020, tail 1021-3
  float* ohb = out + OFF_OH + (size_t)tok * NE;
  if (lane == 0) ohb[0] = (id == 0) ? 1.0f : 0.0f;
  if (lane < 3)  ohb[1021 + lane] = (id == 1021 + lane) ? 1.0f : 0.0f;
  #pragma unroll
  for (int it = 0; it < 4; ++it) {
    int j = it * 64 + lane;
    if (j < 255) {
      int c0 = 1 + 4 * j;
      float4 v;
      v.x = (c0 + 0 == id) ? 1.0f : 0.0f;
      v.y = (c0 + 1 == id) ? 1.0f : 0.0f;
      v.z = (c0 + 2 == id) ? 1.0f : 0.0f;
      v.w = (c0 + 3 == id) ? 1.0f : 0.0f;
      ((float4*)(ohb + 1))[j] = v;             // ohb+1 is 16B-aligned
    }
  }

  #pragma unroll
  for (int off = 32; off; off >>= 1) lsum += __shfl_down(lsum, off, 64);
  __shared__ double lred[4];
  if (lane == 0) lred[tl] = lsum;
  __syncthreads();
  if (t == 0)
    unsafeAtomicAdd(&lossacc[blockIdx.x & 255],
                    lred[0] + lred[1] + lred[2] + lred[3]);
}

// ------------------------------------------------ histogram (LDS-privatized)
__global__ __launch_bounds__(256) void hist_k(const int* __restrict__ idxw,
                                              int* __restrict__ counts) {
  __shared__ int lc[NE];
  for (int i = threadIdx.x; i < NE; i += 256) lc[i] = 0;
  __syncthreads();
  const int stride = gridDim.x * 256;
  for (int i = blockIdx.x * 256 + threadIdx.x; i < NT; i += stride)
    atomicAdd(&lc[idxw[i]], 1);
  __syncthreads();
  for (int i = threadIdx.x; i < NE; i += 256) {
    int v = lc[i];
    if (v) atomicAdd(&counts[i], v);
  }
}

// ------------------------------- exclusive prefix sum (wave-parallel, exact)
__global__ __launch_bounds__(256) void scan_k(const int* __restrict__ counts,
                                              int* __restrict__ offsets) {
  const int t = threadIdx.x;            // 256 threads, 4 codes each
  const int lane = t & 63, w = t >> 6;
  int4 c = ((const int4*)counts)[t];
  int s = c.x + c.y + c.z + c.w;
  int v = s;                            // inclusive wave scan
  #pragma unroll
  for (int off = 1; off < 64; off <<= 1) {
    int u = __shfl_up(v, off, 64);
    if (lane >= off) v += u;
  }
  __shared__ int wsum[4];
  if (lane == 63) wsum[w] = v;
  __syncthreads();
  int base = 0;
  #pragma unroll
  for (int i = 0; i < 4; ++i) if (i < w) base += wsum[i];
  int excl = base + v - s;              // exclusive prefix of this thread
  int4 o;
  o.x = excl;
  o.y = o.x + c.x;
  o.z = o.y + c.y;
  o.w = o.z + c.z;
  ((int4*)offsets)[t] = o;
}

// -------------------------------------------------- scatter tokens into buckets
__global__ __launch_bounds__(256) void scatter_k(
    const int* __restrict__ idxw, const int* __restrict__ offsets,
    int* __restrict__ cursor, int* __restrict__ bucket,
    float* __restrict__ out) {
  int i = blockIdx.x * 256 + threadIdx.x;
  int id = idxw[i];
  out[OFF_IDX + i] = (float)id;
  int pos = atomicAdd(&cursor[id], 1);
  bucket[offsets[id] + pos] = i;
}

// ------------------- per-code segment sum (no atomics) fused with EMA update
__global__ __launch_bounds__(256) void segsum_k(
    const float* __restrict__ z, const float* __restrict__ nmat,
    const float* __restrict__ mmat, const int* __restrict__ counts,
    const int* __restrict__ offsets, const int* __restrict__ bucket,
    float* __restrict__ out) {
  const int j = blockIdx.x, t = threadIdx.x;
  const int cnt = counts[j], off = offsets[j];
  float s = 0.f;
  int i = 0;
  for (; i + 4 <= cnt; i += 4) {
    int t0 = bucket[off + i + 0], t1 = bucket[off + i + 1];
    int t2 = bucket[off + i + 2], t3 = bucket[off + i + 3];
    float a = z[(size_t)t0 * ED + t];
    float b = z[(size_t)t1 * ED + t];
    float c = z[(size_t)t2 * ED + t];
    float d = z[(size_t)t3 * ED + t];
    s += a; s += b; s += c; s += d;
  }
  for (; i < cnt; ++i) s += z[(size_t)bucket[off + i] * ED + t];

  float newn = nmat[j] * 0.99f + (float)cnt * 0.01f;
  if (t == 0) out[OFF_NN + j] = newn;
  const size_t o = (size_t)j * ED + t;
  float newm = 0.99f * mmat[o] + 0.01f * s;
  out[OFF_NM + o]   = newm;
  out[OFF_NEMB + o] = newm / newn;
}

// ------------------------------------------------------- scalar finalizers
__global__ __launch_bounds__(256) void scalars_k(
    const double* __restrict__ lossacc, const int* __restrict__ counts,
    float* __restrict__ out) {
  const int t = threadIdx.x;
  double lsum = lossacc[t];
  double h = 0.0;
  for (int c = t; c < NE; c += 256) {
    double e = (double)counts[c] / (double)NT;
    h += e * log(e + 1e-10);
  }
  #pragma unroll
  for (int off = 32; off; off >>= 1) {
    lsum += __shfl_down(lsum, off, 64);
    h    += __shfl_down(h,    off, 64);
  }
  __shared__ double sl[4], sh[4];
  if ((t & 63) == 0) { sl[t >> 6] = lsum; sh[t >> 6] = h; }
  __syncthreads();
  if (t == 0) {
    double mean = (sl[0] + sl[1] + sl[2] + sl[3]) / (double)((size_t)NT * ED);
    out[OFF_QL]  = (float)mean;
    out[OFF_CL]  = (float)(0.25 * mean);
    out[OFF_PPL] = (float)exp(-(sh[0] + sh[1] + sh[2] + sh[3]));
  }
}

// ------------------------------------------------------------------ launch
extern "C" void kernel_launch(void* const* d_in, const int* in_sizes, int n_in,
                              void* d_out, int out_size, void* d_ws, size_t ws_size,
                              hipStream_t stream) {
  const float* z    = (const float*)d_in[0];
  const float* emb  = (const float*)d_in[1];
  const float* nmat = (const float*)d_in[2];
  const float* mmat = (const float*)d_in[3];
  float* out = (float*)d_out;
  char*  ws  = (char*)d_ws;

  // ws layout (byte offsets):
  //   0       lossacc  double[256]  (2 KB)
  //   2048    nflag    int (zeroed by memset)
  //   4096    counts   int[1024]
  //   8192    cursor   int[1024]
  //   12288   offsets  int[1024]
  //   16384   bucket   int[131072]  (512 KB)
  //   540672  idxw     int[131072]  (512 KB)
  //   1064960 znorm    float[131072] (512 KB)
  //   1589248 enorm    float[1024]  (4 KB)
  //   1593344 eswz     f16 swizzled tiles (512 KB)
  //   2117632 flaglist int[131072]  (512 KB)
  double* lossacc = (double*)ws;
  int*    nflag   = (int*)(ws + 2048);
  int*    counts  = (int*)(ws + 4096);
  int*    cursor  = (int*)(ws + 8192);
  int*    offsets = (int*)(ws + 12288);
  int*    bucket  = (int*)(ws + 16384);
  int*    idxw    = (int*)(ws + 540672);
  float*  znorm   = (float*)(ws + 1064960);
  float*  enorm   = (float*)(ws + 1589248);
  char*   eswz    = ws + 1593344;
  int*    flaglist= (int*)(ws + 2117632);

  hipMemsetAsync(ws, 0, 12288, stream);  // lossacc + nflag + counts + cursor

  hipLaunchKernelGGL(rownorm_k, dim3(NT / 4), dim3(256), 0, stream, z, znorm, NT);
  hipLaunchKernelGGL(rownorm_k, dim3(NE / 4), dim3(256), 0, stream, emb, enorm, NE);
  hipLaunchKernelGGL(eprep_k, dim3(NE / 8), dim3(256), 0, stream, emb, eswz);
  hipLaunchKernelGGL(argmin_coarse_k, dim3(NT / 128), dim3(256), 0, stream,
                     z, eswz, enorm, idxw, nflag, flaglist);
  hipLaunchKernelGGL(argmin_refine_k, dim3(NT / 16), dim3(256), 0, stream,
                     z, emb, znorm, enorm, nflag, flaglist, idxw);
  hipLaunchKernelGGL(zq_oh_k, dim3(NT / 4), dim3(256), 0, stream,
                     z, emb, idxw, out, lossacc);
  hipLaunchKernelGGL(hist_k, dim3(64), dim3(256), 0, stream, idxw, counts);
  hipLaunchKernelGGL(scan_k, dim3(1), dim3(256), 0, stream, counts, offsets);
  hipLaunchKernelGGL(scatter_k, dim3(NT / 256), dim3(256), 0, stream,
                     idxw, offsets, cursor, bucket, out);
  hipLaunchKernelGGL(segsum_k, dim3(NE), dim3(256), 0, stream,
                     z, nmat, mmat, counts, offsets, bucket, out);
  hipLaunchKernelGGL(scalars_k, dim3(1), dim3(256), 0, stream,
                     lossacc, counts, out);
}